// Round 4
// baseline (16.042 us; speedup 1.0000x reference)
//
#include <hip/hip_runtime.h>

// PointQuantizer: nearest-cell-center quantization on a regular 32^3 grid.
// enc = i*1024 + j*32 + l, i = clamp(floor((x+1)*16), 0, 31)  — exact
// equivalent of the reference argmin over the 32768 regular grid centers.
//
// Structure (1 block per batch row, 1024 threads, TWO lgkm-only barriers):
//   1. LDS occupancy bitmap (1024 words) via ds_or — each voxel written
//      EXACTLY ONCE with its final value (+-0.8), coalesced float4 stores.
//   2. Sort: each wave bitonic-sorts its 64 enc values ascending in
//      registers (__shfl_xor, no barriers), publishes to LDS; then ONE
//      barrier and every thread computes its global output position by
//      ranking against the other 15 sorted runs (7-probe binary searches,
//      15 independent LDS-read chains). Earlier runs counted with <=,
//      later with <  => ranks are an exact permutation of 0..1023.
//   Barriers use raw s_barrier + lgkmcnt(0) (never vmcnt) so the 128 KB
//   of voxel stores drain under the ranking phase.

#define VW 32          // voxel grid resolution
#define VK (VW*VW*VW)  // 32768 voxels
#define NPTS 1024      // points per batch row
#define NB 4           // batch
#define NWORDS (VK/32) // 1024 bitmap words

#define BARRIER_LDS() asm volatile("s_waitcnt lgkmcnt(0)\n\ts_barrier" ::: "memory")

__global__ __launch_bounds__(NPTS) void pq_kernel(const float* __restrict__ x,
                                                  float* __restrict__ out) {
    const int b = blockIdx.x;
    const int t = threadIdx.x;
    const int lane = t & 63;
    const int wave = t >> 6;

    float* enc_out = out + b * NPTS;                   // (NPTS) f32
    float* vox = out + NB * NPTS + (size_t)b * VK;     // this row's (VK)

    __shared__ unsigned bm[NWORDS];                    // 4 KiB bitmap
    __shared__ int sb[NPTS];                           // 4 KiB sorted runs

    bm[t] = 0u;

    // --- cell index (separable nearest-center on regular grid) ---
    const float* p = x + (size_t)(b * NPTS + t) * 3;
    float px = p[0], py = p[1], pz = p[2];
    int i = min(max((int)floorf((px + 1.0f) * 16.0f), 0), VW - 1);
    int j = min(max((int)floorf((py + 1.0f) * 16.0f), 0), VW - 1);
    int l = min(max((int)floorf((pz + 1.0f) * 16.0f), 0), VW - 1);
    int v = i * (VW * VW) + j * VW + l;

    BARRIER_LDS();                           // bm zeroed
    atomicOr(&bm[v >> 5], 1u << (v & 31));   // ds_or (lgkm-counted)

    // --- wave-local ascending bitonic sort, registers only ---
    // using `lane` (not t): at k=64 (lane&64)==0 always -> every wave asc.
    #pragma unroll
    for (int k = 2; k <= 64; k <<= 1) {
        #pragma unroll
        for (int jj = k >> 1; jj > 0; jj >>= 1) {
            int pv = __shfl_xor(v, jj);
            bool keepmin = (((lane & jj) == 0) == ((lane & k) == 0));
            v = keepmin ? min(v, pv) : max(v, pv);
        }
    }

    sb[t] = v;        // run `wave` occupies sb[wave*64 .. +64), ascending
    BARRIER_LDS();    // bitmap complete AND runs published

    // --- voxel expansion: issued first, drains under the ranking below ---
    float4* v4 = (float4*)vox;
    #pragma unroll
    for (int g = 0; g < 8; ++g) {
        int m = g * NPTS + t;                        // float4 idx: voxels 4m..
        unsigned nib = bm[m >> 3] >> ((m & 7) * 4);  // 8 lanes broadcast-share
        float4 f;
        f.x = (nib & 1u) ? 0.8f : -0.8f;
        f.y = (nib & 2u) ? 0.8f : -0.8f;
        f.z = (nib & 4u) ? 0.8f : -0.8f;
        f.w = (nib & 8u) ? 0.8f : -0.8f;
        v4[m] = f;
    }

    // --- 16-way merge by ranking: rank = lane + sum over other runs ---
    // earlier runs: count(<= v); later runs: count(< v). 6-step branchless
    // binary search + 1 correction probe (count can be 64 = 65 outcomes).
    int rank = lane;
    #pragma unroll
    for (int s = 0; s < 16; ++s) {
        if (s == wave) continue;                 // wave-uniform branch
        const int* run = &sb[s * 64];
        const bool le = (s < wave);              // wave-uniform
        int pos = 0;
        #pragma unroll
        for (int w = 32; w >= 1; w >>= 1) {
            int c = run[pos + w - 1];
            bool take = le ? (c <= v) : (c < v);
            pos += take ? w : 0;
        }
        int c = run[pos < 63 ? pos : 63];        // pos in [0,63]
        pos += (le ? (c <= v) : (c < v)) && (pos == 63);
        rank += pos;
    }

    enc_out[rank] = (float)v;                    // permutation scatter
}

extern "C" void kernel_launch(void* const* d_in, const int* in_sizes, int n_in,
                              void* d_out, int out_size, void* d_ws, size_t ws_size,
                              hipStream_t stream) {
    const float* x = (const float*)d_in[0];   // (4, 1024, 3) f32
    // d_in[1] = grid_points (32768, 3) f32 — not needed (regular grid)
    float* out = (float*)d_out;               // enc (4,1024) ++ voxel (4,32768)

    pq_kernel<<<NB, NPTS, 0, stream>>>(x, out);
}

// Round 5
// 11.031 us; speedup vs baseline: 1.4544x; 1.4544x over previous
//
#include <hip/hip_runtime.h>

// PointQuantizer: nearest-cell-center quantization on a regular 32^3 grid.
// enc = i*1024 + j*32 + l, i = clamp(floor((x+1)*16), 0, 31)  — exact
// equivalent of the reference argmin over the 32768 regular grid centers.
//
// Grid: 16 blocks = 4 rows x 4 parts, 256 threads each.
//   - ALL blocks: build the row's LDS occupancy bitmap (1024 ds_or), then
//     expand ONE QUARTER of the voxel slab (32 KB of coalesced float4
//     stores) — spreads the store drain over 4 CUs/row instead of 1.
//   - part==0 blocks additionally sort the 1024 enc values:
//     4 items/lane bitonic (pos = wave*256 + r*64 + lane):
//       jj<=32  -> __shfl_xor          (in-register, no barrier)
//       jj=64/128 -> intra-lane reg pair compare-exchange (free)
//       jj=256/512 -> LDS mailbox, ping-pong buffers -> only THREE
//                     barrier stages total (k=512:256; k=1024:512,256)
//     Cross-wave direction bits are wave-uniform (scalar branch).
// Barriers are raw s_barrier + lgkmcnt(0) only (never vmcnt), so voxel
// stores drain under the remaining sort work.

#define VW 32
#define VK (VW*VW*VW)   // 32768
#define NPTS 1024
#define NB 4

#define BARRIER_LDS() asm volatile("s_waitcnt lgkmcnt(0)\n\ts_barrier" ::: "memory")

__device__ __forceinline__ int enc3(float a, float b, float c) {
    int i = min(max((int)floorf((a + 1.0f) * 16.0f), 0), VW - 1);
    int j = min(max((int)floorf((b + 1.0f) * 16.0f), 0), VW - 1);
    int l = min(max((int)floorf((c + 1.0f) * 16.0f), 0), VW - 1);
    return i * (VW * VW) + j * VW + l;
}

__global__ __launch_bounds__(256) void pq_kernel(const float* __restrict__ x,
                                                 float* __restrict__ out) {
    const int blk  = blockIdx.x;
    const int b    = blk >> 2;          // batch row
    const int part = blk & 3;           // voxel quarter; part 0 also sorts
    const int t    = threadIdx.x;
    const int lane = t & 63;
    const int wave = t >> 6;

    float* enc_out = out + b * NPTS;
    float* vox = out + NB * NPTS + (size_t)b * VK;

    __shared__ unsigned bm[VK / 32];    // 4 KiB occupancy bitmap
    __shared__ int sx[2][NPTS];         // 8 KiB mailbox ping-pong

    ((uint4*)bm)[t] = make_uint4(0u, 0u, 0u, 0u);

    // --- load 4 points (48 B, 3x float4), compute 4 cell indices ---
    const float4* x4 = (const float4*)(x + (size_t)b * NPTS * 3);
    float4 q0 = x4[3 * t], q1 = x4[3 * t + 1], q2 = x4[3 * t + 2];
    int v[4];
    v[0] = enc3(q0.x, q0.y, q0.z);
    v[1] = enc3(q0.w, q1.x, q1.y);
    v[2] = enc3(q1.z, q1.w, q2.x);
    v[3] = enc3(q2.y, q2.z, q2.w);

    BARRIER_LDS();                                  // bm zeroed
    #pragma unroll
    for (int r = 0; r < 4; ++r)
        atomicOr(&bm[v[r] >> 5], 1u << (v[r] & 31));

    // --- in-register / shfl compare-exchange step (jj <= 128) ---
    auto step = [&](int k, int jj) {
        if (jj >= 64) {                 // intra-lane register pair
            int d = jj >> 6;            // r-xor mask: 1 or 2
            #pragma unroll
            for (int rb = 0; rb < 4; ++rb) {
                if (rb & d) continue;
                int rl = rb, rh = rb | d;
                int pos = (wave << 8) | (rl << 6) | lane;
                bool asc = ((pos & k) == 0);
                int lo = min(v[rl], v[rh]), hi = max(v[rl], v[rh]);
                v[rl] = asc ? lo : hi;
                v[rh] = asc ? hi : lo;
            }
        } else {                        // cross-lane shuffle
            #pragma unroll
            for (int r = 0; r < 4; ++r) {
                int pos = (wave << 8) | (r << 6) | lane;
                int pv = __shfl_xor(v[r], jj);
                bool keepmin = ((pos & jj) == 0) == ((pos & k) == 0);
                v[r] = keepmin ? min(v[r], pv) : max(v[r], pv);
            }
        }
    };

    if (part == 0) {
        // phase 1: k = 2..256 fully in-register (36 steps, no barriers)
        #pragma unroll
        for (int k = 2; k <= 256; k <<= 1)
            #pragma unroll
            for (int jj = k >> 1; jj > 0; jj >>= 1)
                step(k, jj);
        // k=512, jj=256: publish to mailbox 0
        #pragma unroll
        for (int r = 0; r < 4; ++r)
            sx[0][(wave << 8) | (r << 6) | lane] = v[r];
    }

    BARRIER_LDS();   // bitmap complete (all blocks); mailbox 0 ready (part 0)

    // --- expand my quarter: each voxel written once, final value ---
    {
        float4* v4 = (float4*)vox;
        #pragma unroll
        for (int g = 0; g < 8; ++g) {
            int m = part * 2048 + g * 256 + t;           // float4 index
            unsigned nib = bm[m >> 3] >> ((m & 7) * 4);  // 8-lane broadcast
            float4 f;
            f.x = (nib & 1u) ? 0.8f : -0.8f;
            f.y = (nib & 2u) ? 0.8f : -0.8f;
            f.z = (nib & 4u) ? 0.8f : -0.8f;
            f.w = (nib & 8u) ? 0.8f : -0.8f;
            v4[m] = f;
        }
    }

    if (part != 0) return;

    // --- cross-wave mailbox stage: read partner, compare (wave-uniform dir) ---
    auto xread = [&](int k, int jj, int buf) {
        int wm = jj >> 8;                               // wave xor mask
        bool keepmin = ((wave & wm) == 0) == ((wave & (k >> 8)) == 0);
        #pragma unroll
        for (int r = 0; r < 4; ++r) {
            int pv = sx[buf][((wave ^ wm) << 8) | (r << 6) | lane];
            v[r] = keepmin ? min(v[r], pv) : max(v[r], pv);
        }
    };
    auto xwrite = [&](int buf) {
        #pragma unroll
        for (int r = 0; r < 4; ++r)
            sx[buf][(wave << 8) | (r << 6) | lane] = v[r];
    };

    // k=512: jj=256 (mailbox 0 already published), then jj=128..1 in-register
    xread(512, 256, 0);
    #pragma unroll
    for (int jj = 128; jj > 0; jj >>= 1) step(512, jj);

    // k=1024: jj=512 (mailbox 1), jj=256 (mailbox 0), then jj=128..1
    xwrite(1);
    BARRIER_LDS();
    xread(1024, 512, 1);
    xwrite(0);
    BARRIER_LDS();
    xread(1024, 256, 0);
    #pragma unroll
    for (int jj = 128; jj > 0; jj >>= 1) step(1024, jj);

    // --- write sorted enc (coalesced per r) ---
    #pragma unroll
    for (int r = 0; r < 4; ++r)
        enc_out[(wave << 8) | (r << 6) | lane] = (float)v[r];
}

extern "C" void kernel_launch(void* const* d_in, const int* in_sizes, int n_in,
                              void* d_out, int out_size, void* d_ws, size_t ws_size,
                              hipStream_t stream) {
    const float* x = (const float*)d_in[0];   // (4, 1024, 3) f32
    // d_in[1] = grid_points (32768, 3) f32 — not needed (regular grid)
    float* out = (float*)d_out;               // enc (4,1024) ++ voxel (4,32768)

    pq_kernel<<<NB * 4, 256, 0, stream>>>(x, out);
}